// Round 1
// baseline (1016.886 us; speedup 1.0000x reference)
//
#include <hip/hip_runtime.h>

#define NNODES 50000
#define NEDGES 600000
#define NGRAPHS 512
#define HID 128
#define NLAYERS 4
#define BN_EPS 1e-5f

// ---------------------------------------------------------------------------
// CSR build
// ---------------------------------------------------------------------------
__global__ void k_count_deg(const int* __restrict__ dst, int* __restrict__ deg, int E) {
    int e = blockIdx.x * blockDim.x + threadIdx.x;
    if (e < E) atomicAdd(&deg[dst[e]], 1);
}

// block-wise inclusive scan (512 threads), writes exclusive per-element + block sum
__global__ void k_scan1(const int* __restrict__ deg, int* __restrict__ exg,
                        int* __restrict__ bsum, int n) {
    __shared__ int s[512];
    int tid = threadIdx.x;
    int i = blockIdx.x * 512 + tid;
    int v = (i < n) ? deg[i] : 0;
    s[tid] = v;
    __syncthreads();
    for (int off = 1; off < 512; off <<= 1) {
        int t = (tid >= off) ? s[tid - off] : 0;
        __syncthreads();
        s[tid] += t;
        __syncthreads();
    }
    if (i < n) exg[i] = s[tid] - v;
    if (tid == 511) bsum[blockIdx.x] = s[511];
}

// single-block scan of block sums (nb <= 128), in-place -> exclusive
__global__ void k_scan2(int* __restrict__ bsum, int nb) {
    __shared__ int s[128];
    int tid = threadIdx.x;
    int v = (tid < nb) ? bsum[tid] : 0;
    s[tid] = v;
    __syncthreads();
    for (int off = 1; off < 128; off <<= 1) {
        int t = (tid >= off) ? s[tid - off] : 0;
        __syncthreads();
        s[tid] += t;
        __syncthreads();
    }
    if (tid < nb) bsum[tid] = s[tid] - v;
}

__global__ void k_scan3(const int* __restrict__ exg, const int* __restrict__ bsum,
                        const int* __restrict__ deg,
                        int* __restrict__ rowptr, int* __restrict__ cursor,
                        float* __restrict__ inv_deg, int n, int E) {
    int i = blockIdx.x * blockDim.x + threadIdx.x;
    if (i < n) {
        int r = exg[i] + bsum[i >> 9];
        rowptr[i] = r;
        cursor[i] = r;
        int d = deg[i];
        inv_deg[i] = 1.0f / (float)max(d, 1);
        if (i == 0) rowptr[n] = E;
    }
}

__global__ void k_fill_csr(const int* __restrict__ src, const int* __restrict__ dst,
                           int* __restrict__ cursor, int* __restrict__ csr_src, int E) {
    int e = blockIdx.x * blockDim.x + threadIdx.x;
    if (e < E) {
        int pos = atomicAdd(&cursor[dst[e]], 1);
        csr_src[pos] = src[e];
    }
}

// ---------------------------------------------------------------------------
// Mean aggregation: one wave (64 lanes) per node, float2 per lane
// ---------------------------------------------------------------------------
__global__ void k_aggregate(const float* __restrict__ x, const int* __restrict__ csr_src,
                            const int* __restrict__ rowptr, const float* __restrict__ inv_deg,
                            float* __restrict__ agg) {
    int lane = threadIdx.x & 63;
    int wid = threadIdx.x >> 6;
    int node = blockIdx.x * 4 + wid;
    // grid sized exactly: 50000/4 = 12500 blocks
    int beg = rowptr[node];
    int end = rowptr[node + 1];
    const float2* xr = (const float2*)x;
    float2 acc = make_float2(0.f, 0.f);
    for (int e = beg; e < end; ++e) {
        int s = csr_src[e];
        float2 v = xr[s * 64 + lane];
        acc.x += v.x;
        acc.y += v.y;
    }
    float idg = inv_deg[node];
    acc.x *= idg;
    acc.y *= idg;
    ((float2*)agg)[node * 64 + lane] = acc;
}

// ---------------------------------------------------------------------------
// GEMM: h[M,128] = agg @ Wl^T + bl + x @ Wr^T   (M=50000, K=128 per pass)
// block: 256 threads, 64-row tile. Each thread: 8 rows x 4 cols.
// ---------------------------------------------------------------------------
__launch_bounds__(256) __global__
void k_gemm(const float* __restrict__ Agg, const float* __restrict__ Xc,
            const float* __restrict__ Wl, const float* __restrict__ Wr,
            const float* __restrict__ bl, float* __restrict__ Hout, int M) {
    __shared__ float As[64][132];
    __shared__ float Ws[32][132];
    int t = threadIdx.x;
    int cg = t & 31;       // col group: cols j0..j0+3
    int rg = t >> 5;       // row group: rows rg*8 .. rg*8+7
    int j0 = cg * 4;
    int m0 = blockIdx.x * 64;

    float acc[8][4];
    float4 b4 = *(const float4*)(bl + j0);
    #pragma unroll
    for (int i = 0; i < 8; ++i) {
        acc[i][0] = b4.x; acc[i][1] = b4.y; acc[i][2] = b4.z; acc[i][3] = b4.w;
    }

    for (int p = 0; p < 2; ++p) {
        const float* A = p ? Xc : Agg;
        const float* W = p ? Wr : Wl;
        // stage A tile: 64 rows x 128 cols
        #pragma unroll
        for (int it = 0; it < 8; ++it) {
            int s = t + it * 256;       // float4 slot, 2048 total
            int r = s >> 5;
            int cv = s & 31;
            int row = m0 + r;
            float4 v = make_float4(0.f, 0.f, 0.f, 0.f);
            if (row < M) v = *(const float4*)(A + row * 128 + cv * 4);
            *(float4*)&As[r][cv * 4] = v;
        }
        __syncthreads();
        for (int kc = 0; kc < 4; ++kc) {
            // stage W chunk transposed: Ws[k][j] = W[j*128 + kc*32 + k]
            #pragma unroll
            for (int it = 0; it < 16; ++it) {
                int j = (t >> 5) + it * 8;
                int k = t & 31;
                Ws[k][j] = W[j * 128 + kc * 32 + k];
            }
            __syncthreads();
            #pragma unroll
            for (int k4 = 0; k4 < 8; ++k4) {
                float4 w0 = *(const float4*)&Ws[k4 * 4 + 0][j0];
                float4 w1 = *(const float4*)&Ws[k4 * 4 + 1][j0];
                float4 w2 = *(const float4*)&Ws[k4 * 4 + 2][j0];
                float4 w3 = *(const float4*)&Ws[k4 * 4 + 3][j0];
                #pragma unroll
                for (int i = 0; i < 8; ++i) {
                    float4 a = *(const float4*)&As[rg * 8 + i][kc * 32 + k4 * 4];
                    acc[i][0] += a.x * w0.x + a.y * w1.x + a.z * w2.x + a.w * w3.x;
                    acc[i][1] += a.x * w0.y + a.y * w1.y + a.z * w2.y + a.w * w3.y;
                    acc[i][2] += a.x * w0.z + a.y * w1.z + a.z * w2.z + a.w * w3.z;
                    acc[i][3] += a.x * w0.w + a.y * w1.w + a.z * w2.w + a.w * w3.w;
                }
            }
            __syncthreads();
        }
    }
    #pragma unroll
    for (int i = 0; i < 8; ++i) {
        int row = m0 + rg * 8 + i;
        if (row < M) {
            *(float4*)(Hout + row * 128 + j0) =
                make_float4(acc[i][0], acc[i][1], acc[i][2], acc[i][3]);
        }
    }
}

// ---------------------------------------------------------------------------
// BatchNorm stats: partial column sums/sumsq per block, then finalize
// ---------------------------------------------------------------------------
__global__ void k_bnstats1(const float* __restrict__ h, float2* __restrict__ partials, int n) {
    int t = threadIdx.x;
    int c = t & 127;
    int half = t >> 7;
    float s = 0.f, s2 = 0.f;
    for (int r = blockIdx.x * 2 + half; r < n; r += 512) {
        float v = h[r * 128 + c];
        s += v;
        s2 += v * v;
    }
    __shared__ float rs[256], rq[256];
    rs[t] = s; rq[t] = s2;
    __syncthreads();
    if (t < 128) {
        partials[blockIdx.x * 128 + t] = make_float2(rs[t] + rs[t + 128], rq[t] + rq[t + 128]);
    }
}

__global__ void k_bnstats2(const float2* __restrict__ partials,
                           const float* __restrict__ gamma, const float* __restrict__ beta,
                           float* __restrict__ scale, float* __restrict__ shift, int n) {
    int c = threadIdx.x;  // 128 threads
    float s = 0.f, s2 = 0.f;
    for (int b = 0; b < 256; ++b) {
        float2 p = partials[b * 128 + c];
        s += p.x;
        s2 += p.y;
    }
    float inv_n = 1.0f / (float)n;
    float mu = s * inv_n;
    float var = s2 * inv_n - mu * mu;
    float is = rsqrtf(var + BN_EPS);
    float g = gamma[c] * is;
    scale[c] = g;
    shift[c] = beta[c] - mu * g;
}

__global__ void k_bnrelu(float* __restrict__ h, const float* __restrict__ scale,
                         const float* __restrict__ shift) {
    int idx = blockIdx.x * blockDim.x + threadIdx.x;  // float4 index, grid exact
    int cv = idx & 31;
    float4 sc = ((const float4*)scale)[cv];
    float4 sh = ((const float4*)shift)[cv];
    float4 v = ((float4*)h)[idx];
    v.x = fmaxf(v.x * sc.x + sh.x, 0.f);
    v.y = fmaxf(v.y * sc.y + sh.y, 0.f);
    v.z = fmaxf(v.z * sc.z + sh.z, 0.f);
    v.w = fmaxf(v.w * sc.w + sh.w, 0.f);
    ((float4*)h)[idx] = v;
}

// ---------------------------------------------------------------------------
// Pool + classifier: one block per graph (batch is sorted)
// ---------------------------------------------------------------------------
__global__ void k_pool_cls(const float* __restrict__ x, const int* __restrict__ batch,
                           const float* __restrict__ W1, const float* __restrict__ b1,
                           const float* __restrict__ W2, const float* __restrict__ b2,
                           float* __restrict__ out, int n) {
    int g = blockIdx.x;
    int t = threadIdx.x;  // 128 threads
    // lower_bound(batch, g) and lower_bound(batch, g+1)
    int lo = 0, hi = n;
    while (lo < hi) { int mid = (lo + hi) >> 1; if (batch[mid] < g) lo = mid + 1; else hi = mid; }
    int start = lo;
    lo = start; hi = n;
    while (lo < hi) { int mid = (lo + hi) >> 1; if (batch[mid] < g + 1) lo = mid + 1; else hi = mid; }
    int end = lo;
    int cnt = end - start;

    float s = 0.f;
    for (int r = start; r < end; ++r) s += x[r * 128 + t];
    float inv = 1.0f / (float)max(cnt, 1);

    __shared__ float P[128];
    __shared__ float H1[64];
    P[t] = s * inv;
    __syncthreads();
    if (t < 64) {
        float a = b1[t];
        #pragma unroll 4
        for (int k = 0; k < 128; ++k) a += P[k] * W1[t * 128 + k];
        H1[t] = fmaxf(a, 0.f);
    }
    __syncthreads();
    if (t < 10) {
        float a = b2[t];
        #pragma unroll 4
        for (int k = 0; k < 64; ++k) a += H1[k] * W2[t * 64 + k];
        out[g * 10 + t] = a;
    }
}

// ---------------------------------------------------------------------------
// launch
// ---------------------------------------------------------------------------
extern "C" void kernel_launch(void* const* d_in, const int* in_sizes, int n_in,
                              void* d_out, int out_size, void* d_ws, size_t ws_size,
                              hipStream_t stream) {
    const float* x_in  = (const float*)d_in[0];
    const int*   ei    = (const int*)d_in[1];
    const int*   batch = (const int*)d_in[2];
    const float* Wl    = (const float*)d_in[3];
    const float* bl    = (const float*)d_in[4];
    const float* Wr    = (const float*)d_in[5];
    const float* gamma = (const float*)d_in[6];
    const float* beta  = (const float*)d_in[7];
    const float* W1    = (const float*)d_in[8];
    const float* b1    = (const float*)d_in[9];
    const float* W2    = (const float*)d_in[10];
    const float* b2    = (const float*)d_in[11];
    float* out = (float*)d_out;

    const int N = NNODES, E = NEDGES;
    const int* src = ei;
    const int* dst = ei + E;

    // workspace carve (256B aligned)
    char* p = (char*)d_ws;
    auto alloc = [&](size_t bytes) {
        char* r = p;
        p += (bytes + 255) & ~(size_t)255;
        return r;
    };
    float*  agg      = (float*)alloc((size_t)N * HID * 4);
    float*  bufB     = (float*)alloc((size_t)N * HID * 4);
    float*  bufC     = (float*)alloc((size_t)N * HID * 4);
    int*    deg      = (int*)alloc((size_t)N * 4);
    float*  inv_deg  = (float*)alloc((size_t)N * 4);
    int*    rowptr   = (int*)alloc((size_t)(N + 1) * 4);
    int*    cursor   = (int*)alloc((size_t)N * 4);
    int*    csr_src  = (int*)alloc((size_t)E * 4);
    int*    exg      = (int*)alloc((size_t)N * 4);
    int*    bsum     = (int*)alloc(512);
    float2* partials = (float2*)alloc((size_t)256 * 128 * 8);
    float*  scale    = (float*)alloc(HID * 4);
    float*  shift    = (float*)alloc(HID * 4);

    // ---- CSR build ----
    hipMemsetAsync(deg, 0, (size_t)N * 4, stream);
    int eb = (E + 255) / 256;
    k_count_deg<<<eb, 256, 0, stream>>>(dst, deg, E);
    int nb = (N + 511) / 512;  // 98
    k_scan1<<<nb, 512, 0, stream>>>(deg, exg, bsum, N);
    k_scan2<<<1, 128, 0, stream>>>(bsum, nb);
    k_scan3<<<(N + 255) / 256, 256, 0, stream>>>(exg, bsum, deg, rowptr, cursor, inv_deg, N, E);
    k_fill_csr<<<eb, 256, 0, stream>>>(src, dst, cursor, csr_src, E);

    // ---- layers ----
    const float* xcur = x_in;
    for (int l = 0; l < NLAYERS; ++l) {
        float* h = (l & 1) ? bufC : bufB;
        k_aggregate<<<N / 4, 256, 0, stream>>>(xcur, csr_src, rowptr, inv_deg, agg);
        k_gemm<<<(N + 63) / 64, 256, 0, stream>>>(agg, xcur,
                                                  Wl + (size_t)l * HID * HID,
                                                  Wr + (size_t)l * HID * HID,
                                                  bl + (size_t)l * HID, h, N);
        k_bnstats1<<<256, 256, 0, stream>>>(h, partials, N);
        k_bnstats2<<<1, 128, 0, stream>>>(partials, gamma + (size_t)l * HID,
                                          beta + (size_t)l * HID, scale, shift, N);
        k_bnrelu<<<(N * HID / 4) / 256, 256, 0, stream>>>(h, scale, shift);
        xcur = h;
    }

    // ---- pool + classifier ----
    k_pool_cls<<<NGRAPHS, 128, 0, stream>>>(xcur, batch, W1, b1, W2, b2, out, N);
}

// Round 2
// 694.017 us; speedup vs baseline: 1.4652x; 1.4652x over previous
//
#include <hip/hip_runtime.h>

#define NNODES 50000
#define MPAD   50048   // 391 * 128
#define NEDGES 600000
#define NGRAPHS 512
#define HID 128
#define NLAYERS 4
#define BN_EPS 1e-5f

typedef __bf16 bf16x8 __attribute__((ext_vector_type(8)));
typedef float  f32x4  __attribute__((ext_vector_type(4)));

__device__ __forceinline__ unsigned short f2bf(float f) {
    unsigned u = __builtin_bit_cast(unsigned, f);
    unsigned r = (u + 0x7fffu + ((u >> 16) & 1u)) >> 16;
    return (unsigned short)r;
}
__device__ __forceinline__ float bf2f(unsigned short u) {
    return __builtin_bit_cast(float, (unsigned)u << 16);
}

// ---------------------------------------------------------------------------
// CSR build
// ---------------------------------------------------------------------------
__global__ void k_count_deg(const int* __restrict__ dst, int* __restrict__ deg, int E) {
    int e = blockIdx.x * blockDim.x + threadIdx.x;
    if (e < E) atomicAdd(&deg[dst[e]], 1);
}

__global__ void k_scan1(const int* __restrict__ deg, int* __restrict__ exg,
                        int* __restrict__ bsum, int n) {
    __shared__ int s[512];
    int tid = threadIdx.x;
    int i = blockIdx.x * 512 + tid;
    int v = (i < n) ? deg[i] : 0;
    s[tid] = v;
    __syncthreads();
    for (int off = 1; off < 512; off <<= 1) {
        int t = (tid >= off) ? s[tid - off] : 0;
        __syncthreads();
        s[tid] += t;
        __syncthreads();
    }
    if (i < n) exg[i] = s[tid] - v;
    if (tid == 511) bsum[blockIdx.x] = s[511];
}

__global__ void k_scan2(int* __restrict__ bsum, int nb) {
    __shared__ int s[128];
    int tid = threadIdx.x;
    int v = (tid < nb) ? bsum[tid] : 0;
    s[tid] = v;
    __syncthreads();
    for (int off = 1; off < 128; off <<= 1) {
        int t = (tid >= off) ? s[tid - off] : 0;
        __syncthreads();
        s[tid] += t;
        __syncthreads();
    }
    if (tid < nb) bsum[tid] = s[tid] - v;
}

__global__ void k_scan3(const int* __restrict__ exg, const int* __restrict__ bsum,
                        const int* __restrict__ deg,
                        int* __restrict__ rowptr, int* __restrict__ cursor,
                        float* __restrict__ inv_deg, int n, int E) {
    int i = blockIdx.x * blockDim.x + threadIdx.x;
    if (i < n) {
        int r = exg[i] + bsum[i >> 9];
        rowptr[i] = r;
        cursor[i] = r;
        int d = deg[i];
        inv_deg[i] = 1.0f / (float)max(d, 1);
        if (i == 0) rowptr[n] = E;
    }
}

__global__ void k_fill_csr(const int* __restrict__ src, const int* __restrict__ dst,
                           int* __restrict__ cursor, int* __restrict__ csr_src, int E) {
    int e = blockIdx.x * blockDim.x + threadIdx.x;
    if (e < E) {
        int pos = atomicAdd(&cursor[dst[e]], 1);
        csr_src[pos] = src[e];
    }
}

// ---------------------------------------------------------------------------
// split fp32 -> (hi, lo) bf16 pair
// ---------------------------------------------------------------------------
__global__ void k_split(const float* __restrict__ x,
                        unsigned short* __restrict__ xhi, unsigned short* __restrict__ xlo) {
    int idx = blockIdx.x * 256 + threadIdx.x;   // float4 index; grid exact (1.6M/256)
    float4 v = ((const float4*)x)[idx];
    ushort4 h, l;
    h.x = f2bf(v.x); l.x = f2bf(v.x - bf2f(h.x));
    h.y = f2bf(v.y); l.y = f2bf(v.y - bf2f(h.y));
    h.z = f2bf(v.z); l.z = f2bf(v.z - bf2f(h.z));
    h.w = f2bf(v.w); l.w = f2bf(v.w - bf2f(h.w));
    *(ushort4*)(xhi + (size_t)idx * 4) = h;
    *(ushort4*)(xlo + (size_t)idx * 4) = l;
}

// ---------------------------------------------------------------------------
// W prepack into MFMA B-fragment order, split hi/lo.
// Layout: off(l,ks,nf,hl,lane,j) = (((l*64 + ks*8 + nf)*2 + hl)*64 + lane)*8 + j
// B frag element j: W_cat[n = nf*16 + (lane&15)][k = ks*32 + (lane>>4)*8 + j]
// W_cat[n][k] = k<128 ? Wl[n][k] : Wr[n][k-128]
// ---------------------------------------------------------------------------
__global__ void k_wpack(const float* __restrict__ Wl, const float* __restrict__ Wr,
                        unsigned short* __restrict__ Wpk) {
    int lane = threadIdx.x;          // 64 threads
    int b = blockIdx.x;              // 256 blocks = 4 layers * 8 ks * 8 nf
    int nf = b & 7, ks = (b >> 3) & 7, l = b >> 6;
    int n = nf * 16 + (lane & 15);
    int k = ks * 32 + (lane >> 4) * 8;
    const float* W = (k < 128) ? (Wl + (size_t)l * HID * HID)
                               : (Wr + (size_t)l * HID * HID - 128);
    size_t base = ((((size_t)l * 64 + ks * 8 + nf) * 2) * 64 + lane) * 8;
    #pragma unroll
    for (int j = 0; j < 8; ++j) {
        float w = W[(size_t)n * 128 + k + j];
        unsigned short h = f2bf(w);
        unsigned short lo = f2bf(w - bf2f(h));
        Wpk[base + j] = h;
        Wpk[base + 512 + j] = lo;
    }
}

// ---------------------------------------------------------------------------
// Mean aggregation reading hi/lo bf16, writing hi/lo bf16 (exact fp32 accum)
// ---------------------------------------------------------------------------
__global__ void k_aggregate2(const unsigned short* __restrict__ xhi,
                             const unsigned short* __restrict__ xlo,
                             const int* __restrict__ csr_src, const int* __restrict__ rowptr,
                             const float* __restrict__ inv_deg,
                             unsigned short* __restrict__ ahi, unsigned short* __restrict__ alo) {
    int lane = threadIdx.x & 63;
    int wid = threadIdx.x >> 6;
    int node = blockIdx.x * 4 + wid;   // grid exact: 12500
    int beg = rowptr[node];
    int end = rowptr[node + 1];
    float a0 = 0.f, a1 = 0.f;
    for (int e = beg; e < end; ++e) {
        int s = csr_src[e];
        unsigned uh = *(const unsigned*)(xhi + (size_t)s * 128 + lane * 2);
        unsigned ul = *(const unsigned*)(xlo + (size_t)s * 128 + lane * 2);
        a0 += bf2f((unsigned short)(uh & 0xffff)) + bf2f((unsigned short)(ul & 0xffff));
        a1 += bf2f((unsigned short)(uh >> 16))    + bf2f((unsigned short)(ul >> 16));
    }
    float idg = inv_deg[node];
    a0 *= idg; a1 *= idg;
    unsigned short h0 = f2bf(a0), l0 = f2bf(a0 - bf2f(h0));
    unsigned short h1 = f2bf(a1), l1 = f2bf(a1 - bf2f(h1));
    *(unsigned*)(ahi + (size_t)node * 128 + lane * 2) = (unsigned)h0 | ((unsigned)h1 << 16);
    *(unsigned*)(alo + (size_t)node * 128 + lane * 2) = (unsigned)l0 | ((unsigned)l1 << 16);
}

// ---------------------------------------------------------------------------
// MFMA GEMM: H[m][n] = sum_k Acat[m][k] * Wcat[n][k] + bl[n]
//   Acat = [agg | x], K=256, split-bf16: Ah*Wh + Al*Wh + Ah*Wl
// Block: 256 thr = 4 waves; wave owns 32 rows x 128 cols. Grid 391 (MPAD/128).
// No LDS; A frags per-lane from global, W frags prepacked & coalesced (L2-hot).
// ---------------------------------------------------------------------------
__launch_bounds__(256) __global__
void k_mfma_gemm(const unsigned short* __restrict__ Ahi0, const unsigned short* __restrict__ Alo0,
                 const unsigned short* __restrict__ Ahi1, const unsigned short* __restrict__ Alo1,
                 const unsigned short* __restrict__ Wpk, const float* __restrict__ bl,
                 float* __restrict__ Hout) {
    int wid = threadIdx.x >> 6;
    int lane = threadIdx.x & 63;
    int m0 = blockIdx.x * 128 + wid * 32;
    int r = lane & 15;
    int kg = lane >> 4;

    f32x4 acc[2][8];
    #pragma unroll
    for (int nf = 0; nf < 8; ++nf) {
        float b = bl[nf * 16 + r];
        acc[0][nf] = f32x4{b, b, b, b};
        acc[1][nf] = f32x4{b, b, b, b};
    }

    #pragma unroll
    for (int ks = 0; ks < 8; ++ks) {
        const unsigned short* hi = (ks < 4) ? Ahi0 : Ahi1;
        const unsigned short* lo = (ks < 4) ? Alo0 : Alo1;
        int kc = (ks & 3) * 32 + kg * 8;
        bf16x8 ah0 = *(const bf16x8*)(hi + (size_t)(m0 + r) * 128 + kc);
        bf16x8 al0 = *(const bf16x8*)(lo + (size_t)(m0 + r) * 128 + kc);
        bf16x8 ah1 = *(const bf16x8*)(hi + (size_t)(m0 + 16 + r) * 128 + kc);
        bf16x8 al1 = *(const bf16x8*)(lo + (size_t)(m0 + 16 + r) * 128 + kc);
        const unsigned short* wb = Wpk + (size_t)ks * 8192;
        #pragma unroll
        for (int nf = 0; nf < 8; ++nf) {
            bf16x8 bh = *(const bf16x8*)(wb + (size_t)nf * 1024 + lane * 8);
            bf16x8 bl2 = *(const bf16x8*)(wb + (size_t)nf * 1024 + 512 + lane * 8);
            acc[0][nf] = __builtin_amdgcn_mfma_f32_16x16x32_bf16(ah0, bh,  acc[0][nf], 0, 0, 0);
            acc[0][nf] = __builtin_amdgcn_mfma_f32_16x16x32_bf16(al0, bh,  acc[0][nf], 0, 0, 0);
            acc[0][nf] = __builtin_amdgcn_mfma_f32_16x16x32_bf16(ah0, bl2, acc[0][nf], 0, 0, 0);
            acc[1][nf] = __builtin_amdgcn_mfma_f32_16x16x32_bf16(ah1, bh,  acc[1][nf], 0, 0, 0);
            acc[1][nf] = __builtin_amdgcn_mfma_f32_16x16x32_bf16(al1, bh,  acc[1][nf], 0, 0, 0);
            acc[1][nf] = __builtin_amdgcn_mfma_f32_16x16x32_bf16(ah1, bl2, acc[1][nf], 0, 0, 0);
        }
    }

    // C/D layout (verified, m89): col = lane&15, row = (lane>>4)*4 + reg
    #pragma unroll
    for (int mf = 0; mf < 2; ++mf)
        #pragma unroll
        for (int nf = 0; nf < 8; ++nf)
            #pragma unroll
            for (int g = 0; g < 4; ++g)
                Hout[(size_t)(m0 + mf * 16 + kg * 4 + g) * 128 + nf * 16 + r] = acc[mf][nf][g];
}

// ---------------------------------------------------------------------------
// BatchNorm stats (h is fp32, only first NNODES rows)
// ---------------------------------------------------------------------------
__global__ void k_bnstats1(const float* __restrict__ h, float2* __restrict__ partials, int n) {
    int t = threadIdx.x;
    int c = t & 127;
    int half = t >> 7;
    float s = 0.f, s2 = 0.f;
    for (int r = blockIdx.x * 2 + half; r < n; r += 512) {
        float v = h[(size_t)r * 128 + c];
        s += v;
        s2 += v * v;
    }
    __shared__ float rs[256], rq[256];
    rs[t] = s; rq[t] = s2;
    __syncthreads();
    if (t < 128) {
        partials[blockIdx.x * 128 + t] = make_float2(rs[t] + rs[t + 128], rq[t] + rq[t + 128]);
    }
}

__global__ void k_bnstats2(const float2* __restrict__ partials,
                           const float* __restrict__ gamma, const float* __restrict__ beta,
                           float* __restrict__ scale, float* __restrict__ shift, int n) {
    int c = threadIdx.x;
    float s = 0.f, s2 = 0.f;
    for (int b = 0; b < 256; ++b) {
        float2 p = partials[b * 128 + c];
        s += p.x;
        s2 += p.y;
    }
    float inv_n = 1.0f / (float)n;
    float mu = s * inv_n;
    float var = s2 * inv_n - mu * mu;
    float is = rsqrtf(var + BN_EPS);
    float g = gamma[c] * is;
    scale[c] = g;
    shift[c] = beta[c] - mu * g;
}

// BN + ReLU, write next-layer activations as hi/lo bf16
__global__ void k_bnrelu2(const float* __restrict__ h, const float* __restrict__ scale,
                          const float* __restrict__ shift,
                          unsigned short* __restrict__ xhi, unsigned short* __restrict__ xlo) {
    int idx = blockIdx.x * 256 + threadIdx.x;   // float4 index; grid exact 6250
    int cv = idx & 31;
    float4 sc = ((const float4*)scale)[cv];
    float4 sh = ((const float4*)shift)[cv];
    float4 v = ((const float4*)h)[idx];
    v.x = fmaxf(v.x * sc.x + sh.x, 0.f);
    v.y = fmaxf(v.y * sc.y + sh.y, 0.f);
    v.z = fmaxf(v.z * sc.z + sh.z, 0.f);
    v.w = fmaxf(v.w * sc.w + sh.w, 0.f);
    ushort4 hh, ll;
    hh.x = f2bf(v.x); ll.x = f2bf(v.x - bf2f(hh.x));
    hh.y = f2bf(v.y); ll.y = f2bf(v.y - bf2f(hh.y));
    hh.z = f2bf(v.z); ll.z = f2bf(v.z - bf2f(hh.z));
    hh.w = f2bf(v.w); ll.w = f2bf(v.w - bf2f(hh.w));
    *(ushort4*)(xhi + (size_t)idx * 4) = hh;
    *(ushort4*)(xlo + (size_t)idx * 4) = ll;
}

// ---------------------------------------------------------------------------
// Pool + classifier (reads hi/lo bf16 activations)
// ---------------------------------------------------------------------------
__global__ void k_pool_cls(const unsigned short* __restrict__ xhi,
                           const unsigned short* __restrict__ xlo,
                           const int* __restrict__ batch,
                           const float* __restrict__ W1, const float* __restrict__ b1,
                           const float* __restrict__ W2, const float* __restrict__ b2,
                           float* __restrict__ out, int n) {
    int g = blockIdx.x;
    int t = threadIdx.x;  // 128 threads
    int lo = 0, hi = n;
    while (lo < hi) { int mid = (lo + hi) >> 1; if (batch[mid] < g) lo = mid + 1; else hi = mid; }
    int start = lo;
    lo = start; hi = n;
    while (lo < hi) { int mid = (lo + hi) >> 1; if (batch[mid] < g + 1) lo = mid + 1; else hi = mid; }
    int end = lo;
    int cnt = end - start;

    float s = 0.f;
    for (int r = start; r < end; ++r)
        s += bf2f(xhi[(size_t)r * 128 + t]) + bf2f(xlo[(size_t)r * 128 + t]);
    float inv = 1.0f / (float)max(cnt, 1);

    __shared__ float P[128];
    __shared__ float H1[64];
    P[t] = s * inv;
    __syncthreads();
    if (t < 64) {
        float a = b1[t];
        #pragma unroll 4
        for (int k = 0; k < 128; ++k) a += P[k] * W1[t * 128 + k];
        H1[t] = fmaxf(a, 0.f);
    }
    __syncthreads();
    if (t < 10) {
        float a = b2[t];
        #pragma unroll 4
        for (int k = 0; k < 64; ++k) a += H1[k] * W2[t * 64 + k];
        out[g * 10 + t] = a;
    }
}

// ---------------------------------------------------------------------------
// launch
// ---------------------------------------------------------------------------
extern "C" void kernel_launch(void* const* d_in, const int* in_sizes, int n_in,
                              void* d_out, int out_size, void* d_ws, size_t ws_size,
                              hipStream_t stream) {
    const float* x_in  = (const float*)d_in[0];
    const int*   ei    = (const int*)d_in[1];
    const int*   batch = (const int*)d_in[2];
    const float* Wl    = (const float*)d_in[3];
    const float* bl    = (const float*)d_in[4];
    const float* Wr    = (const float*)d_in[5];
    const float* gamma = (const float*)d_in[6];
    const float* beta  = (const float*)d_in[7];
    const float* W1    = (const float*)d_in[8];
    const float* b1    = (const float*)d_in[9];
    const float* W2    = (const float*)d_in[10];
    const float* b2    = (const float*)d_in[11];
    float* out = (float*)d_out;

    const int N = NNODES, E = NEDGES;
    const int* src = ei;
    const int* dst = ei + E;

    char* p = (char*)d_ws;
    auto alloc = [&](size_t bytes) {
        char* r = p;
        p += (bytes + 255) & ~(size_t)255;
        return r;
    };
    unsigned short* ahi = (unsigned short*)alloc((size_t)MPAD * HID * 2);
    unsigned short* alo = (unsigned short*)alloc((size_t)MPAD * HID * 2);
    unsigned short* xhi = (unsigned short*)alloc((size_t)MPAD * HID * 2);
    unsigned short* xlo = (unsigned short*)alloc((size_t)MPAD * HID * 2);
    float*  h        = (float*)alloc((size_t)MPAD * HID * 4);
    unsigned short* wpk = (unsigned short*)alloc((size_t)NLAYERS * 64 * 2 * 64 * 8 * 2);
    int*    deg      = (int*)alloc((size_t)N * 4);
    float*  inv_deg  = (float*)alloc((size_t)N * 4);
    int*    rowptr   = (int*)alloc((size_t)(N + 1) * 4);
    int*    cursor   = (int*)alloc((size_t)N * 4);
    int*    csr_src  = (int*)alloc((size_t)E * 4);
    int*    exg      = (int*)alloc((size_t)N * 4);
    int*    bsum     = (int*)alloc(512);
    float2* partials = (float2*)alloc((size_t)256 * 128 * 8);
    float*  scale    = (float*)alloc(HID * 4);
    float*  shift    = (float*)alloc(HID * 4);

    // ---- zero pad rows (rows N..MPAD) of activation/agg buffers, once ----
    size_t padoff = (size_t)N * HID * 2;
    size_t padbytes = (size_t)(MPAD - N) * HID * 2;
    hipMemsetAsync(ahi + N * HID, 0, padbytes, stream);
    hipMemsetAsync(alo + N * HID, 0, padbytes, stream);
    hipMemsetAsync(xhi + N * HID, 0, padbytes, stream);
    hipMemsetAsync(xlo + N * HID, 0, padbytes, stream);
    (void)padoff;

    // ---- CSR build ----
    hipMemsetAsync(deg, 0, (size_t)N * 4, stream);
    int eb = (E + 255) / 256;
    k_count_deg<<<eb, 256, 0, stream>>>(dst, deg, E);
    int nb = (N + 511) / 512;
    k_scan1<<<nb, 512, 0, stream>>>(deg, exg, bsum, N);
    k_scan2<<<1, 128, 0, stream>>>(bsum, nb);
    k_scan3<<<(N + 255) / 256, 256, 0, stream>>>(exg, bsum, deg, rowptr, cursor, inv_deg, N, E);
    k_fill_csr<<<eb, 256, 0, stream>>>(src, dst, cursor, csr_src, E);

    // ---- weight prepack + input split ----
    k_wpack<<<NLAYERS * 64, 64, 0, stream>>>(Wl, Wr, wpk);
    k_split<<<(N * HID / 4) / 256, 256, 0, stream>>>(x_in, xhi, xlo);

    // ---- layers ----
    for (int l = 0; l < NLAYERS; ++l) {
        k_aggregate2<<<N / 4, 256, 0, stream>>>(xhi, xlo, csr_src, rowptr, inv_deg, ahi, alo);
        k_mfma_gemm<<<MPAD / 128, 256, 0, stream>>>(ahi, alo, xhi, xlo,
                                                    wpk + (size_t)l * 65536,
                                                    bl + (size_t)l * HID, h);
        k_bnstats1<<<256, 256, 0, stream>>>(h, partials, N);
        k_bnstats2<<<1, 128, 0, stream>>>(partials, gamma + (size_t)l * HID,
                                          beta + (size_t)l * HID, scale, shift, N);
        k_bnrelu2<<<(N * HID / 4) / 256, 256, 0, stream>>>(h, scale, shift, xhi, xlo);
    }

    // ---- pool + classifier ----
    k_pool_cls<<<NGRAPHS, 128, 0, stream>>>(xhi, xlo, batch, W1, b1, W2, b2, out, N);
}

// Round 3
// 538.953 us; speedup vs baseline: 1.8868x; 1.2877x over previous
//
#include <hip/hip_runtime.h>

#define NNODES 50000
#define MPAD   50048   // 391 * 128
#define NEDGES 600000
#define NGRAPHS 512
#define HID 128
#define NLAYERS 4
#define BN_EPS 1e-5f

typedef __bf16 bf16x8 __attribute__((ext_vector_type(8)));
typedef float  f32x4  __attribute__((ext_vector_type(4)));

__device__ __forceinline__ unsigned short f2bf(float f) {
    unsigned u = __builtin_bit_cast(unsigned, f);
    unsigned r = (u + 0x7fffu + ((u >> 16) & 1u)) >> 16;
    return (unsigned short)r;
}
__device__ __forceinline__ float bf2f(unsigned short u) {
    return __builtin_bit_cast(float, (unsigned)u << 16);
}

// ---------------------------------------------------------------------------
// CSR build
// ---------------------------------------------------------------------------
__global__ void k_count_deg(const int* __restrict__ dst, int* __restrict__ deg, int E) {
    int e = blockIdx.x * blockDim.x + threadIdx.x;
    if (e < E) atomicAdd(&deg[dst[e]], 1);
}

__global__ void k_scan1(const int* __restrict__ deg, int* __restrict__ exg,
                        int* __restrict__ bsum, int n) {
    __shared__ int s[512];
    int tid = threadIdx.x;
    int i = blockIdx.x * 512 + tid;
    int v = (i < n) ? deg[i] : 0;
    s[tid] = v;
    __syncthreads();
    for (int off = 1; off < 512; off <<= 1) {
        int t = (tid >= off) ? s[tid - off] : 0;
        __syncthreads();
        s[tid] += t;
        __syncthreads();
    }
    if (i < n) exg[i] = s[tid] - v;
    if (tid == 511) bsum[blockIdx.x] = s[511];
}

__global__ void k_scan2(int* __restrict__ bsum, int nb) {
    __shared__ int s[128];
    int tid = threadIdx.x;
    int v = (tid < nb) ? bsum[tid] : 0;
    s[tid] = v;
    __syncthreads();
    for (int off = 1; off < 128; off <<= 1) {
        int t = (tid >= off) ? s[tid - off] : 0;
        __syncthreads();
        s[tid] += t;
        __syncthreads();
    }
    if (tid < nb) bsum[tid] = s[tid] - v;
}

__global__ void k_scan3(const int* __restrict__ exg, const int* __restrict__ bsum,
                        const int* __restrict__ deg,
                        int* __restrict__ rowptr, int* __restrict__ cursor,
                        float* __restrict__ inv_deg, int n, int E) {
    int i = blockIdx.x * blockDim.x + threadIdx.x;
    if (i < n) {
        int r = exg[i] + bsum[i >> 9];
        rowptr[i] = r;
        cursor[i] = r;
        int d = deg[i];
        inv_deg[i] = 1.0f / (float)max(d, 1);
        if (i == 0) rowptr[n] = E;
    }
}

__global__ void k_fill_csr(const int* __restrict__ src, const int* __restrict__ dst,
                           int* __restrict__ cursor, int* __restrict__ csr_src, int E) {
    int e = blockIdx.x * blockDim.x + threadIdx.x;
    if (e < E) {
        int pos = atomicAdd(&cursor[dst[e]], 1);
        csr_src[pos] = src[e];
    }
}

// ---------------------------------------------------------------------------
// split fp32 -> (hi, lo) bf16 pair
// ---------------------------------------------------------------------------
__global__ void k_split(const float* __restrict__ x,
                        unsigned short* __restrict__ xhi, unsigned short* __restrict__ xlo) {
    int idx = blockIdx.x * 256 + threadIdx.x;   // float4 index; grid exact (1.6M/256)
    float4 v = ((const float4*)x)[idx];
    ushort4 h, l;
    h.x = f2bf(v.x); l.x = f2bf(v.x - bf2f(h.x));
    h.y = f2bf(v.y); l.y = f2bf(v.y - bf2f(h.y));
    h.z = f2bf(v.z); l.z = f2bf(v.z - bf2f(h.z));
    h.w = f2bf(v.w); l.w = f2bf(v.w - bf2f(h.w));
    *(ushort4*)(xhi + (size_t)idx * 4) = h;
    *(ushort4*)(xlo + (size_t)idx * 4) = l;
}

// ---------------------------------------------------------------------------
// W prepack into MFMA B-fragment order, split hi/lo.
// ---------------------------------------------------------------------------
__global__ void k_wpack(const float* __restrict__ Wl, const float* __restrict__ Wr,
                        unsigned short* __restrict__ Wpk) {
    int lane = threadIdx.x;          // 64 threads
    int b = blockIdx.x;              // 256 blocks = 4 layers * 8 ks * 8 nf
    int nf = b & 7, ks = (b >> 3) & 7, l = b >> 6;
    int n = nf * 16 + (lane & 15);
    int k = ks * 32 + (lane >> 4) * 8;
    const float* W = (k < 128) ? (Wl + (size_t)l * HID * HID)
                               : (Wr + (size_t)l * HID * HID - 128);
    size_t base = ((((size_t)l * 64 + ks * 8 + nf) * 2) * 64 + lane) * 8;
    #pragma unroll
    for (int j = 0; j < 8; ++j) {
        float w = W[(size_t)n * 128 + k + j];
        unsigned short h = f2bf(w);
        unsigned short lo = f2bf(w - bf2f(h));
        Wpk[base + j] = h;
        Wpk[base + 512 + j] = lo;
    }
}

// ---------------------------------------------------------------------------
// Mean aggregation: gather HI stream only (bf16 noise averages down ~1/sqrt(deg)),
// fp32 accumulate, write hi/lo split for the MFMA GEMM A-side.
// One wave per node, 2 features per lane (1 dword), edge loop unrolled x4.
// ---------------------------------------------------------------------------
__global__ void k_aggregate3(const unsigned short* __restrict__ xhi,
                             const int* __restrict__ csr_src, const int* __restrict__ rowptr,
                             const float* __restrict__ inv_deg,
                             unsigned short* __restrict__ ahi, unsigned short* __restrict__ alo) {
    int lane = threadIdx.x & 63;
    int wid = threadIdx.x >> 6;
    int node = blockIdx.x * 4 + wid;   // grid exact: 12500
    int beg = rowptr[node];
    int end = rowptr[node + 1];
    float a0 = 0.f, a1 = 0.f;
    float b0 = 0.f, b1 = 0.f, c0 = 0.f, c1 = 0.f, d0 = 0.f, d1 = 0.f;
    int e = beg;
    for (; e + 4 <= end; e += 4) {
        int s0 = csr_src[e], s1 = csr_src[e + 1], s2 = csr_src[e + 2], s3 = csr_src[e + 3];
        unsigned u0 = *(const unsigned*)(xhi + (size_t)s0 * 128 + lane * 2);
        unsigned u1 = *(const unsigned*)(xhi + (size_t)s1 * 128 + lane * 2);
        unsigned u2 = *(const unsigned*)(xhi + (size_t)s2 * 128 + lane * 2);
        unsigned u3 = *(const unsigned*)(xhi + (size_t)s3 * 128 + lane * 2);
        a0 += bf2f((unsigned short)(u0 & 0xffff)); a1 += bf2f((unsigned short)(u0 >> 16));
        b0 += bf2f((unsigned short)(u1 & 0xffff)); b1 += bf2f((unsigned short)(u1 >> 16));
        c0 += bf2f((unsigned short)(u2 & 0xffff)); c1 += bf2f((unsigned short)(u2 >> 16));
        d0 += bf2f((unsigned short)(u3 & 0xffff)); d1 += bf2f((unsigned short)(u3 >> 16));
    }
    for (; e < end; ++e) {
        int s = csr_src[e];
        unsigned u = *(const unsigned*)(xhi + (size_t)s * 128 + lane * 2);
        a0 += bf2f((unsigned short)(u & 0xffff));
        a1 += bf2f((unsigned short)(u >> 16));
    }
    a0 += b0 + c0 + d0;
    a1 += b1 + c1 + d1;
    float idg = inv_deg[node];
    a0 *= idg; a1 *= idg;
    unsigned short h0 = f2bf(a0), l0 = f2bf(a0 - bf2f(h0));
    unsigned short h1 = f2bf(a1), l1 = f2bf(a1 - bf2f(h1));
    *(unsigned*)(ahi + (size_t)node * 128 + lane * 2) = (unsigned)h0 | ((unsigned)h1 << 16);
    *(unsigned*)(alo + (size_t)node * 128 + lane * 2) = (unsigned)l0 | ((unsigned)l1 << 16);
}

// ---------------------------------------------------------------------------
// MFMA GEMM: H[m][n] = sum_k Acat[m][k] * Wcat[n][k] + bl[n]
// ---------------------------------------------------------------------------
__launch_bounds__(256) __global__
void k_mfma_gemm(const unsigned short* __restrict__ Ahi0, const unsigned short* __restrict__ Alo0,
                 const unsigned short* __restrict__ Ahi1, const unsigned short* __restrict__ Alo1,
                 const unsigned short* __restrict__ Wpk, const float* __restrict__ bl,
                 float* __restrict__ Hout) {
    int wid = threadIdx.x >> 6;
    int lane = threadIdx.x & 63;
    int m0 = blockIdx.x * 128 + wid * 32;
    int r = lane & 15;
    int kg = lane >> 4;

    f32x4 acc[2][8];
    #pragma unroll
    for (int nf = 0; nf < 8; ++nf) {
        float b = bl[nf * 16 + r];
        acc[0][nf] = f32x4{b, b, b, b};
        acc[1][nf] = f32x4{b, b, b, b};
    }

    #pragma unroll
    for (int ks = 0; ks < 8; ++ks) {
        const unsigned short* hi = (ks < 4) ? Ahi0 : Ahi1;
        const unsigned short* lo = (ks < 4) ? Alo0 : Alo1;
        int kc = (ks & 3) * 32 + kg * 8;
        bf16x8 ah0 = *(const bf16x8*)(hi + (size_t)(m0 + r) * 128 + kc);
        bf16x8 al0 = *(const bf16x8*)(lo + (size_t)(m0 + r) * 128 + kc);
        bf16x8 ah1 = *(const bf16x8*)(hi + (size_t)(m0 + 16 + r) * 128 + kc);
        bf16x8 al1 = *(const bf16x8*)(lo + (size_t)(m0 + 16 + r) * 128 + kc);
        const unsigned short* wb = Wpk + (size_t)ks * 8192;
        #pragma unroll
        for (int nf = 0; nf < 8; ++nf) {
            bf16x8 bh = *(const bf16x8*)(wb + (size_t)nf * 1024 + lane * 8);
            bf16x8 bl2 = *(const bf16x8*)(wb + (size_t)nf * 1024 + 512 + lane * 8);
            acc[0][nf] = __builtin_amdgcn_mfma_f32_16x16x32_bf16(ah0, bh,  acc[0][nf], 0, 0, 0);
            acc[0][nf] = __builtin_amdgcn_mfma_f32_16x16x32_bf16(al0, bh,  acc[0][nf], 0, 0, 0);
            acc[0][nf] = __builtin_amdgcn_mfma_f32_16x16x32_bf16(ah0, bl2, acc[0][nf], 0, 0, 0);
            acc[1][nf] = __builtin_amdgcn_mfma_f32_16x16x32_bf16(ah1, bh,  acc[1][nf], 0, 0, 0);
            acc[1][nf] = __builtin_amdgcn_mfma_f32_16x16x32_bf16(al1, bh,  acc[1][nf], 0, 0, 0);
            acc[1][nf] = __builtin_amdgcn_mfma_f32_16x16x32_bf16(ah1, bl2, acc[1][nf], 0, 0, 0);
        }
    }

    // C/D layout: col = lane&15, row = (lane>>4)*4 + reg
    #pragma unroll
    for (int mf = 0; mf < 2; ++mf)
        #pragma unroll
        for (int nf = 0; nf < 8; ++nf)
            #pragma unroll
            for (int g = 0; g < 4; ++g)
                Hout[(size_t)(m0 + mf * 16 + kg * 4 + g) * 128 + nf * 16 + r] = acc[mf][nf][g];
}

// ---------------------------------------------------------------------------
// BatchNorm stats
// ---------------------------------------------------------------------------
__global__ void k_bnstats1(const float* __restrict__ h, float2* __restrict__ partials, int n) {
    int t = threadIdx.x;
    int c = t & 127;
    int half = t >> 7;
    float s = 0.f, s2 = 0.f;
    for (int r = blockIdx.x * 2 + half; r < n; r += 512) {
        float v = h[(size_t)r * 128 + c];
        s += v;
        s2 += v * v;
    }
    __shared__ float rs[256], rq[256];
    rs[t] = s; rq[t] = s2;
    __syncthreads();
    if (t < 128) {
        partials[blockIdx.x * 128 + t] = make_float2(rs[t] + rs[t + 128], rq[t] + rq[t + 128]);
    }
}

__global__ void k_bnstats2(const float2* __restrict__ partials,
                           const float* __restrict__ gamma, const float* __restrict__ beta,
                           float* __restrict__ scale, float* __restrict__ shift, int n) {
    int c = threadIdx.x;
    float s = 0.f, s2 = 0.f;
    for (int b = 0; b < 256; ++b) {
        float2 p = partials[b * 128 + c];
        s += p.x;
        s2 += p.y;
    }
    float inv_n = 1.0f / (float)n;
    float mu = s * inv_n;
    float var = s2 * inv_n - mu * mu;
    float is = rsqrtf(var + BN_EPS);
    float g = gamma[c] * is;
    scale[c] = g;
    shift[c] = beta[c] - mu * g;
}

// BN + ReLU, write next-layer activations as hi/lo bf16
__global__ void k_bnrelu2(const float* __restrict__ h, const float* __restrict__ scale,
                          const float* __restrict__ shift,
                          unsigned short* __restrict__ xhi, unsigned short* __restrict__ xlo) {
    int idx = blockIdx.x * 256 + threadIdx.x;   // float4 index; grid exact 6250
    int cv = idx & 31;
    float4 sc = ((const float4*)scale)[cv];
    float4 sh = ((const float4*)shift)[cv];
    float4 v = ((const float4*)h)[idx];
    v.x = fmaxf(v.x * sc.x + sh.x, 0.f);
    v.y = fmaxf(v.y * sc.y + sh.y, 0.f);
    v.z = fmaxf(v.z * sc.z + sh.z, 0.f);
    v.w = fmaxf(v.w * sc.w + sh.w, 0.f);
    ushort4 hh, ll;
    hh.x = f2bf(v.x); ll.x = f2bf(v.x - bf2f(hh.x));
    hh.y = f2bf(v.y); ll.y = f2bf(v.y - bf2f(hh.y));
    hh.z = f2bf(v.z); ll.z = f2bf(v.z - bf2f(hh.z));
    hh.w = f2bf(v.w); ll.w = f2bf(v.w - bf2f(hh.w));
    *(ushort4*)(xhi + (size_t)idx * 4) = hh;
    *(ushort4*)(xlo + (size_t)idx * 4) = ll;
}

// ---------------------------------------------------------------------------
// Pool + classifier (reads hi/lo bf16 activations)
// ---------------------------------------------------------------------------
__global__ void k_pool_cls(const unsigned short* __restrict__ xhi,
                           const unsigned short* __restrict__ xlo,
                           const int* __restrict__ batch,
                           const float* __restrict__ W1, const float* __restrict__ b1,
                           const float* __restrict__ W2, const float* __restrict__ b2,
                           float* __restrict__ out, int n) {
    int g = blockIdx.x;
    int t = threadIdx.x;  // 128 threads
    int lo = 0, hi = n;
    while (lo < hi) { int mid = (lo + hi) >> 1; if (batch[mid] < g) lo = mid + 1; else hi = mid; }
    int start = lo;
    lo = start; hi = n;
    while (lo < hi) { int mid = (lo + hi) >> 1; if (batch[mid] < g + 1) lo = mid + 1; else hi = mid; }
    int end = lo;
    int cnt = end - start;

    float s = 0.f;
    for (int r = start; r < end; ++r)
        s += bf2f(xhi[(size_t)r * 128 + t]) + bf2f(xlo[(size_t)r * 128 + t]);
    float inv = 1.0f / (float)max(cnt, 1);

    __shared__ float P[128];
    __shared__ float H1[64];
    P[t] = s * inv;
    __syncthreads();
    if (t < 64) {
        float a = b1[t];
        #pragma unroll 4
        for (int k = 0; k < 128; ++k) a += P[k] * W1[t * 128 + k];
        H1[t] = fmaxf(a, 0.f);
    }
    __syncthreads();
    if (t < 10) {
        float a = b2[t];
        #pragma unroll 4
        for (int k = 0; k < 64; ++k) a += H1[k] * W2[t * 64 + k];
        out[g * 10 + t] = a;
    }
}

// ---------------------------------------------------------------------------
// launch
// ---------------------------------------------------------------------------
extern "C" void kernel_launch(void* const* d_in, const int* in_sizes, int n_in,
                              void* d_out, int out_size, void* d_ws, size_t ws_size,
                              hipStream_t stream) {
    const float* x_in  = (const float*)d_in[0];
    const int*   ei    = (const int*)d_in[1];
    const int*   batch = (const int*)d_in[2];
    const float* Wl    = (const float*)d_in[3];
    const float* bl    = (const float*)d_in[4];
    const float* Wr    = (const float*)d_in[5];
    const float* gamma = (const float*)d_in[6];
    const float* beta  = (const float*)d_in[7];
    const float* W1    = (const float*)d_in[8];
    const float* b1    = (const float*)d_in[9];
    const float* W2    = (const float*)d_in[10];
    const float* b2    = (const float*)d_in[11];
    float* out = (float*)d_out;

    const int N = NNODES, E = NEDGES;
    const int* src = ei;
    const int* dst = ei + E;

    char* p = (char*)d_ws;
    auto alloc = [&](size_t bytes) {
        char* r = p;
        p += (bytes + 255) & ~(size_t)255;
        return r;
    };
    unsigned short* ahi = (unsigned short*)alloc((size_t)MPAD * HID * 2);
    unsigned short* alo = (unsigned short*)alloc((size_t)MPAD * HID * 2);
    unsigned short* xhi = (unsigned short*)alloc((size_t)MPAD * HID * 2);
    unsigned short* xlo = (unsigned short*)alloc((size_t)MPAD * HID * 2);
    float*  h        = (float*)alloc((size_t)MPAD * HID * 4);
    unsigned short* wpk = (unsigned short*)alloc((size_t)NLAYERS * 64 * 2 * 64 * 8 * 2);
    int*    deg      = (int*)alloc((size_t)N * 4);
    float*  inv_deg  = (float*)alloc((size_t)N * 4);
    int*    rowptr   = (int*)alloc((size_t)(N + 1) * 4);
    int*    cursor   = (int*)alloc((size_t)N * 4);
    int*    csr_src  = (int*)alloc((size_t)E * 4);
    int*    exg      = (int*)alloc((size_t)N * 4);
    int*    bsum     = (int*)alloc(512);
    float2* partials = (float2*)alloc((size_t)256 * 128 * 8);
    float*  scale    = (float*)alloc(HID * 4);
    float*  shift    = (float*)alloc(HID * 4);

    // ---- zero pad rows (rows N..MPAD) of activation/agg buffers, once ----
    size_t padbytes = (size_t)(MPAD - N) * HID * 2;
    hipMemsetAsync(ahi + N * HID, 0, padbytes, stream);
    hipMemsetAsync(alo + N * HID, 0, padbytes, stream);
    hipMemsetAsync(xhi + N * HID, 0, padbytes, stream);
    hipMemsetAsync(xlo + N * HID, 0, padbytes, stream);

    // ---- CSR build ----
    hipMemsetAsync(deg, 0, (size_t)N * 4, stream);
    int eb = (E + 255) / 256;
    k_count_deg<<<eb, 256, 0, stream>>>(dst, deg, E);
    int nb = (N + 511) / 512;
    k_scan1<<<nb, 512, 0, stream>>>(deg, exg, bsum, N);
    k_scan2<<<1, 128, 0, stream>>>(bsum, nb);
    k_scan3<<<(N + 255) / 256, 256, 0, stream>>>(exg, bsum, deg, rowptr, cursor, inv_deg, N, E);
    k_fill_csr<<<eb, 256, 0, stream>>>(src, dst, cursor, csr_src, E);

    // ---- weight prepack + input split ----
    k_wpack<<<NLAYERS * 64, 64, 0, stream>>>(Wl, Wr, wpk);
    k_split<<<(N * HID / 4) / 256, 256, 0, stream>>>(x_in, xhi, xlo);

    // ---- layers ----
    for (int l = 0; l < NLAYERS; ++l) {
        k_aggregate3<<<N / 4, 256, 0, stream>>>(xhi, csr_src, rowptr, inv_deg, ahi, alo);
        k_mfma_gemm<<<MPAD / 128, 256, 0, stream>>>(ahi, alo, xhi, xlo,
                                                    wpk + (size_t)l * 65536,
                                                    bl + (size_t)l * HID, h);
        k_bnstats1<<<256, 256, 0, stream>>>(h, partials, N);
        k_bnstats2<<<1, 128, 0, stream>>>(partials, gamma + (size_t)l * HID,
                                          beta + (size_t)l * HID, scale, shift, N);
        k_bnrelu2<<<(N * HID / 4) / 256, 256, 0, stream>>>(h, scale, shift, xhi, xlo);
    }

    // ---- pool + classifier ----
    k_pool_cls<<<NGRAPHS, 128, 0, stream>>>(xhi, xlo, batch, W1, b1, W2, b2, out, N);
}